// Round 7
// baseline (49.980 us; speedup 1.0000x reference)
//
#include <hip/hip_runtime.h>

// PCEN: EMA over time then (x / (M+eps)^alpha + delta)^r - delta^r
// x: [B=64, T=2048, F=128] float32, out same shape/type.
//
// Exact 3-kernel chunked scan (EMA is affine: m_end = a^L * m_in + local).
// R7 changes vs R4 (45.9 us): float2 vector loads (512 B/wave-request),
// CH=128 chunks of L=16 (8192 waves -> up to 32 waves/CU; R1/R2 showed
// 4 w/CU -> 2.0 TB/s, 16 w/CU -> 3.1 TB/s: concurrency-bound), VGPR caps
// via launch_bounds, plain stores (R6's nontemporal stores regressed).
//  K1: thread=(b,c,f2) computes local chunk carry from 0-init
//      (chunk 0 exact via m[0]=x[0]).
//  K2: thread=(b,f) serially composes 128 chunk carries -> exact carry-in
//      per chunk (4 MiB in d_ws).
//  K3: thread=(b,c,f2) replays its chunk from the exact carry-in, emits
//      PCEN. x re-read is L3-served (64 MiB << 256 MiB L3).

namespace {
constexpr int B = 64;
constexpr int T = 2048;
constexpr int F = 128;
constexpr int F2 = F / 2;      // float2 groups per row
constexpr int CH = 128;        // chunks per sequence
constexpr int L = T / CH;      // 16
constexpr float S   = 0.025f;
constexpr float A1  = 0.975f;
constexpr float AL  = 0.6669197082f;   // 0.975^16
constexpr float EPS = 1e-6f;
constexpr float ALPHA = 0.98f;
constexpr float DR  = 1.1892071150027210667f;  // 2^0.25
}

__global__ __launch_bounds__(256, 8) void k_carry(const float* __restrict__ x,
                                                  float* __restrict__ carry) {
    const int tid = blockIdx.x * 256 + threadIdx.x;   // [b][c][f2], f2 fastest
    const int f2 = tid & (F2 - 1);
    const int cb = tid >> 6;
    const int c  = cb & (CH - 1);
    const int b  = cb >> 7;

    const float2* p = (const float2*)(x + ((size_t)(b * T + c * L)) * F) + f2;
    float2 m;
    if (c == 0) m = p[0];               // m[0]=x[0]; t=0 update re-yields x[0]
    else        m = make_float2(0.f, 0.f);
    #pragma unroll 8
    for (int t = 0; t < L; ++t) {
        float2 xv = p[(size_t)t * F2];
        m.x = fmaf(A1, m.x, S * xv.x);
        m.y = fmaf(A1, m.y, S * xv.y);
    }
    ((float2*)carry)[tid] = m;          // layout [b][c][f]
}

__global__ __launch_bounds__(256) void k_prefix(const float* __restrict__ carry,
                                                float* __restrict__ m_in) {
    const int tid = blockIdx.x * 256 + threadIdx.x;   // 8192 threads: b*F+f
    const int f = tid & (F - 1);
    const int b = tid >> 7;
    const float* cr = carry + (size_t)b * CH * F + f;
    float*       mi = m_in  + (size_t)b * CH * F + f;
    float me = cr[0];                    // exact end of chunk 0
    #pragma unroll 8
    for (int c = 1; c < CH; ++c) {
        mi[(size_t)c * F] = me;          // carry-in for chunk c
        me = fmaf(AL, me, cr[(size_t)c * F]);
    }
}

__global__ __launch_bounds__(256, 4) void k_final(const float* __restrict__ x,
                                                  const float* __restrict__ m_in,
                                                  float* __restrict__ out) {
    const int tid = blockIdx.x * 256 + threadIdx.x;
    const int f2 = tid & (F2 - 1);
    const int cb = tid >> 6;
    const int c  = cb & (CH - 1);
    const int b  = cb >> 7;

    const size_t rowbase = ((size_t)(b * T + c * L)) * F;
    const float2* p = (const float2*)(x + rowbase) + f2;
    float2*       q = (float2*)(out + rowbase) + f2;

    float2 m = (c == 0) ? p[0] : ((const float2*)m_in)[tid];
    #pragma unroll
    for (int t = 0; t < L; ++t) {
        float2 xv = p[(size_t)t * F2];
        m.x = fmaf(A1, m.x, S * xv.x);
        m.y = fmaf(A1, m.y, S * xv.y);
        // x / (M+eps)^alpha == x * exp2(-alpha * log2(M+eps))
        float ix = exp2f(-ALPHA * log2f(m.x + EPS));
        float iy = exp2f(-ALPHA * log2f(m.y + EPS));
        float ux = fmaf(xv.x, ix, 2.0f);
        float uy = fmaf(xv.y, iy, 2.0f);
        float2 r = make_float2(sqrtf(sqrtf(ux)) - DR, sqrtf(sqrtf(uy)) - DR);
        q[(size_t)t * F2] = r;
    }
}

extern "C" void kernel_launch(void* const* d_in, const int* in_sizes, int n_in,
                              void* d_out, int out_size, void* d_ws, size_t ws_size,
                              hipStream_t stream) {
    const float* x   = (const float*)d_in[0];
    float*       out = (float*)d_out;
    float* carry = (float*)d_ws;                        // 4 MiB
    float* m_in  = carry + (size_t)B * CH * F;          // 4 MiB

    const int total2 = B * CH * F2;                     // 524288 threads
    k_carry <<<dim3(total2 / 256), dim3(256), 0, stream>>>(x, carry);
    k_prefix<<<dim3(B * F / 256), dim3(256), 0, stream>>>(carry, m_in);
    k_final <<<dim3(total2 / 256), dim3(256), 0, stream>>>(x, m_in, out);
}